// Round 1
// baseline (991.001 us; speedup 1.0000x reference)
//
#include <hip/hip_runtime.h>
#include <stdint.h>
#include <stddef.h>

// Problem constants
#define N_ROWS 32768
#define D_IN   3000
#define KPAD   3072   // D_IN padded to multiple of 32 (zero pad)
#define H0     1024
#define H1     256
#define NCLUST 20

typedef __attribute__((ext_vector_type(8))) short short8;   // 8 x bf16 (4 VGPRs)
typedef __attribute__((ext_vector_type(4))) float f32x4;

// fp32 -> bf16 (round-to-nearest-even), manual to avoid header type friction
__device__ inline unsigned short f2bf(float f) {
    union { float f; unsigned u; } v; v.f = f;
    unsigned r = v.u + 0x7fffu + ((v.u >> 16) & 1u);
    return (unsigned short)(r >> 16);
}

// async global->LDS, 16B per lane; lds dest must be wave-uniform base (+lane*16 implicit)
__device__ inline void async16(const unsigned short* g, unsigned short* l) {
    __builtin_amdgcn_global_load_lds(
        (const __attribute__((address_space(1))) unsigned int*)(g),
        (__attribute__((address_space(3))) unsigned int*)(l),
        16, 0, 0);
}

// ---------------------------------------------------------------------------
// x [32768 x 3000] fp32  ->  xb [32768 x 3072] bf16, zero-padded cols 3000..3071
// one thread per 4 elements; 3000 = 750 float4 per row (16B aligned rows)
// ---------------------------------------------------------------------------
__global__ __launch_bounds__(256)
void cvt_x(const float* __restrict__ x, unsigned short* __restrict__ xb) {
    int idx = blockIdx.x * 256 + threadIdx.x;     // [0, 32768*768)
    int m  = idx / 768;
    int k4 = idx - m * 768;                        // float4-group within padded row
    if (m >= N_ROWS) return;
    uint2 out;
    if (k4 < 750) {
        const float4 v = ((const float4*)x)[(size_t)m * 750 + k4];
        out.x = ((unsigned)f2bf(v.x)) | (((unsigned)f2bf(v.y)) << 16);
        out.y = ((unsigned)f2bf(v.z)) | (((unsigned)f2bf(v.w)) << 16);
    } else {
        out.x = 0u; out.y = 0u;
    }
    ((uint2*)xb)[(size_t)m * 768 + k4] = out;
}

// ---------------------------------------------------------------------------
// W [rows x cols] fp32 row-major  ->  outT [cols x rowsPad] bf16 (transposed),
// zero-padded rows (k) up to rowsPad. cols must be multiple of 32.
// block (32,8), 32x32 tiles via LDS.
// ---------------------------------------------------------------------------
__global__ __launch_bounds__(256)
void transpose_cvt(const float* __restrict__ W, int rows, int cols, int rowsPad,
                   unsigned short* __restrict__ outT) {
    __shared__ unsigned short tile[32][33];
    const int c0 = blockIdx.x * 32;   // col (n) block
    const int r0 = blockIdx.y * 32;   // row (k) block
    const int tx = threadIdx.x, ty = threadIdx.y;
    #pragma unroll
    for (int i = 0; i < 4; ++i) {
        int r = r0 + ty + i * 8;
        float v = (r < rows) ? W[(size_t)r * cols + c0 + tx] : 0.0f;
        tile[ty + i * 8][tx] = f2bf(v);
    }
    __syncthreads();
    #pragma unroll
    for (int i = 0; i < 4; ++i) {
        int c = c0 + ty + i * 8;
        outT[(size_t)c * rowsPad + r0 + tx] = tile[tx][ty + i * 8];
    }
}

// ---------------------------------------------------------------------------
// C[M x Nn] = A[M x K](bf16) * Bt[Nn x K]^T(bf16) + bias
// EPILOGUE 0: silu -> bf16 store (GEMM1, h)
// EPILOGUE 1: fp32 store (GEMM2, z)
// 128x128 block tile, BK=32, 256 threads = 4 waves (2x2), each wave 64x64
// (4x4 tiles of mfma_f32_16x16x32_bf16). Staging via global_load_lds x16.
// ---------------------------------------------------------------------------
template<int EPILOGUE>
__global__ __launch_bounds__(256)
void gemm_tn(const unsigned short* __restrict__ A,
             const unsigned short* __restrict__ Bt,
             const float* __restrict__ bias,
             void* __restrict__ Cout, int Nn, int K)
{
    __shared__ unsigned short sA[128 * 32];   // [row][k] row-major, 64B rows
    __shared__ unsigned short sB[128 * 32];   // [n][k]   row-major, 64B rows

    const int m0   = blockIdx.y * 128;
    const int n0   = blockIdx.x * 128;
    const int tid  = threadIdx.x;
    const int wave = tid >> 6;
    const int lane = tid & 63;
    const int wm   = wave & 1;    // wave row within 2x2
    const int wn   = wave >> 1;   // wave col within 2x2

    f32x4 acc[4][4];
    #pragma unroll
    for (int i = 0; i < 4; ++i)
        #pragma unroll
        for (int j = 0; j < 4; ++j)
            acc[i][j] = (f32x4){0.f, 0.f, 0.f, 0.f};

    // Staging: each wave fills chunks (2*wave) and (2*wave+1), 16 rows each.
    // Lane covers row = chunk*16 + lane/4, col = (lane%4)*8 elems (16B).
    const int sRow0 = wave * 32 + (lane >> 2);   // chunk 2*wave
    const int sCol  = (lane & 3) * 8;
    const unsigned short* gA0 = A  + (size_t)(m0 + sRow0) * K + sCol;
    const unsigned short* gA1 = gA0 + (size_t)16 * K;
    const unsigned short* gB0 = Bt + (size_t)(n0 + sRow0) * K + sCol;
    const unsigned short* gB1 = gB0 + (size_t)16 * K;
    unsigned short* lA0 = &sA[wave * 1024];      // wave-uniform LDS bases
    unsigned short* lA1 = lA0 + 512;
    unsigned short* lB0 = &sB[wave * 1024];
    unsigned short* lB1 = lB0 + 512;

    // fragment read offsets (elements) in the 128x32 tiles
    const int fa = (wm * 64 + (lane & 15)) * 32 + (lane >> 4) * 8;
    const int fb = (wn * 64 + (lane & 15)) * 32 + (lane >> 4) * 8;

    for (int k0 = 0; k0 < K; k0 += 32) {
        async16(gA0 + k0, lA0);
        async16(gA1 + k0, lA1);
        async16(gB0 + k0, lB0);
        async16(gB1 + k0, lB1);
        __syncthreads();   // drains vmcnt before barrier

        short8 af[4], bf[4];
        #pragma unroll
        for (int t = 0; t < 4; ++t) {
            af[t] = *(const short8*)&sA[fa + t * 16 * 32];
            bf[t] = *(const short8*)&sB[fb + t * 16 * 32];
        }
        #pragma unroll
        for (int i = 0; i < 4; ++i)
            #pragma unroll
            for (int j = 0; j < 4; ++j)
                acc[i][j] = __builtin_amdgcn_mfma_f32_16x16x32_bf16(
                    af[i], bf[j], acc[i][j], 0, 0, 0);
        __syncthreads();
    }

    // Epilogue. C/D layout: col = lane&15, row = (lane>>4)*4 + reg
    const int cr = (lane >> 4) * 4;
    const int cc = lane & 15;
    #pragma unroll
    for (int j = 0; j < 4; ++j) {
        const int col = n0 + wn * 64 + j * 16 + cc;
        const float bv = bias[col];
        #pragma unroll
        for (int i = 0; i < 4; ++i) {
            const int rowBase = m0 + wm * 64 + i * 16 + cr;
            #pragma unroll
            for (int r = 0; r < 4; ++r) {
                float v = acc[i][j][r] + bv;
                if (EPILOGUE == 0) {
                    float s = v / (1.0f + __expf(-v));   // silu
                    ((unsigned short*)Cout)[(size_t)(rowBase + r) * Nn + col] = f2bf(s);
                } else {
                    ((float*)Cout)[(size_t)(rowBase + r) * Nn + col] = v;
                }
            }
        }
    }
}

// ---------------------------------------------------------------------------
// Soft-assign: q[n,k] = (1 + ||z_n - c_k||^2)^-1, row-normalized (V=1).
// One wave per row; clusters cached in LDS; butterfly reduce over 64 lanes.
// ---------------------------------------------------------------------------
__global__ __launch_bounds__(256)
void cluster_kernel(const float* __restrict__ z, const float* __restrict__ clusters,
                    float* __restrict__ q) {
    __shared__ float sc[NCLUST * H1];   // 20 KB
    const int tid = threadIdx.x;
    for (int i = tid; i < NCLUST * H1; i += 256) sc[i] = clusters[i];
    __syncthreads();

    const int wave = tid >> 6, lane = tid & 63;
    const int row = blockIdx.x * 4 + wave;   // grid = 8192 -> 32768 rows exactly

    const float4 zv = ((const float4*)(z + (size_t)row * H1))[lane];

    float myq = 0.0f, qsum = 0.0f;
    #pragma unroll
    for (int k = 0; k < NCLUST; ++k) {
        const float4 cv = ((const float4*)(sc + k * H1))[lane];
        float dx = zv.x - cv.x, dy = zv.y - cv.y;
        float dz = zv.z - cv.z, dw = zv.w - cv.w;
        float p = dx * dx + dy * dy + dz * dz + dw * dw;
        #pragma unroll
        for (int s = 32; s >= 1; s >>= 1) p += __shfl_xor(p, s, 64);
        float qk = 1.0f / (1.0f + p);   // V=1: (1+d2/V)^(-(V+1)/2) = 1/(1+d2)
        qsum += qk;
        myq = (lane == k) ? qk : myq;
    }
    if (lane < NCLUST) q[(size_t)row * NCLUST + lane] = myq / qsum;
}

// ---------------------------------------------------------------------------
extern "C" void kernel_launch(void* const* d_in, const int* in_sizes, int n_in,
                              void* d_out, int out_size, void* d_ws, size_t ws_size,
                              hipStream_t stream) {
    const float* x        = (const float*)d_in[0];
    const float* W1       = (const float*)d_in[1];
    const float* b1       = (const float*)d_in[2];
    const float* W2       = (const float*)d_in[3];
    const float* b2       = (const float*)d_in[4];
    const float* clusters = (const float*)d_in[5];
    float* out = (float*)d_out;   // [32768*256 z fp32][32768*20 q fp32]

    // workspace layout (all 16B aligned)
    unsigned short* xb  = (unsigned short*)d_ws;                  // 32768*3072 bf16
    unsigned short* w1t = xb  + (size_t)N_ROWS * KPAD;            // 1024*3072 bf16 (W1^T padded)
    unsigned short* w2t = w1t + (size_t)H0 * KPAD;                // 256*1024 bf16 (W2^T)
    unsigned short* h   = w2t + (size_t)H1 * H0;                  // 32768*1024 bf16

    // 1) x -> bf16 (padded)
    hipLaunchKernelGGL(cvt_x, dim3((N_ROWS * 768) / 256), dim3(256), 0, stream, x, xb);
    // 2) W1 -> bf16 transposed+padded [1024][3072]
    hipLaunchKernelGGL(transpose_cvt, dim3(H0 / 32, KPAD / 32), dim3(32, 8), 0, stream,
                       W1, D_IN, H0, KPAD, w1t);
    // 3) W2 -> bf16 transposed [256][1024]
    hipLaunchKernelGGL(transpose_cvt, dim3(H1 / 32, H0 / 32), dim3(32, 8), 0, stream,
                       W2, H0, H1, H0, w2t);
    // 4) h = silu(xb @ W1 + b1)  [32768 x 1024] bf16
    hipLaunchKernelGGL((gemm_tn<0>), dim3(H0 / 128, N_ROWS / 128), dim3(256), 0, stream,
                       xb, w1t, b1, (void*)h, H0, KPAD);
    // 5) z = h @ W2 + b2  [32768 x 256] fp32 -> d_out
    hipLaunchKernelGGL((gemm_tn<1>), dim3(H1 / 128, N_ROWS / 128), dim3(256), 0, stream,
                       h, w2t, b2, (void*)out, H1, H0);
    // 6) q soft-assign -> d_out tail
    hipLaunchKernelGGL(cluster_kernel, dim3(N_ROWS / 4), dim3(256), 0, stream,
                       out, clusters, out + (size_t)N_ROWS * H1);
}

// Round 2
// 894.870 us; speedup vs baseline: 1.1074x; 1.1074x over previous
//
#include <hip/hip_runtime.h>
#include <stdint.h>
#include <stddef.h>

// Problem constants
#define N_ROWS 32768
#define D_IN   3000
#define KPAD   3072   // D_IN padded to multiple of 32 (zero pad)
#define H0     1024
#define H1     256
#define NCLUST 20

typedef __attribute__((ext_vector_type(8))) short short8;   // 8 x bf16 (4 VGPRs)
typedef __attribute__((ext_vector_type(4))) float f32x4;

// fp32 -> bf16 (round-to-nearest-even)
__device__ inline unsigned short f2bf(float f) {
    union { float f; unsigned u; } v; v.f = f;
    unsigned r = v.u + 0x7fffu + ((v.u >> 16) & 1u);
    return (unsigned short)(r >> 16);
}

// async global->LDS, 16B per lane; lds dest is wave-uniform base (+lane*16 implicit)
__device__ inline void async16(const unsigned short* g, unsigned short* l) {
    __builtin_amdgcn_global_load_lds(
        (const __attribute__((address_space(1))) unsigned int*)(g),
        (__attribute__((address_space(3))) unsigned int*)(l),
        16, 0, 0);
}

// ---------------------------------------------------------------------------
// x [32768 x 3000] fp32 -> xb [32768 x 3072] bf16, zero-padded cols 3000..3071
// one thread per 8 elements (375*8 = 3000 exactly; groups 375..383 are pad)
// ---------------------------------------------------------------------------
__global__ __launch_bounds__(256)
void cvt_x(const float* __restrict__ x, unsigned short* __restrict__ xb) {
    int idx = blockIdx.x * 256 + threadIdx.x;     // [0, 32768*384)
    int m  = idx / 384;
    int k8 = idx - m * 384;
    uint4 out;
    if (k8 < 375) {
        const float4 v0 = ((const float4*)x)[(size_t)m * 750 + k8 * 2];
        const float4 v1 = ((const float4*)x)[(size_t)m * 750 + k8 * 2 + 1];
        out.x = ((unsigned)f2bf(v0.x)) | (((unsigned)f2bf(v0.y)) << 16);
        out.y = ((unsigned)f2bf(v0.z)) | (((unsigned)f2bf(v0.w)) << 16);
        out.z = ((unsigned)f2bf(v1.x)) | (((unsigned)f2bf(v1.y)) << 16);
        out.w = ((unsigned)f2bf(v1.z)) | (((unsigned)f2bf(v1.w)) << 16);
    } else {
        out.x = 0u; out.y = 0u; out.z = 0u; out.w = 0u;
    }
    ((uint4*)xb)[(size_t)m * 384 + k8] = out;
}

// ---------------------------------------------------------------------------
// W [rows x cols] fp32 row-major -> outT [cols x rowsPad] bf16 (transposed),
// zero-padded rows (k) up to rowsPad. cols must be multiple of 32.
// ---------------------------------------------------------------------------
__global__ __launch_bounds__(256)
void transpose_cvt(const float* __restrict__ W, int rows, int cols, int rowsPad,
                   unsigned short* __restrict__ outT) {
    __shared__ unsigned short tile[32][33];
    const int c0 = blockIdx.x * 32;
    const int r0 = blockIdx.y * 32;
    const int tx = threadIdx.x, ty = threadIdx.y;
    #pragma unroll
    for (int i = 0; i < 4; ++i) {
        int r = r0 + ty + i * 8;
        float v = (r < rows) ? W[(size_t)r * cols + c0 + tx] : 0.0f;
        tile[ty + i * 8][tx] = f2bf(v);
    }
    __syncthreads();
    #pragma unroll
    for (int i = 0; i < 4; ++i) {
        int c = c0 + ty + i * 8;
        outT[(size_t)c * rowsPad + r0 + tx] = tile[tx][ty + i * 8];
    }
}

// ---------------------------------------------------------------------------
// C[M x Nn] = A[M x K](bf16) * Bt[Nn x K]^T(bf16) + bias
// EPILOGUE 0: silu -> bf16 store (GEMM1, h);  EPILOGUE 1: fp32 store (GEMM2, z)
// 128x256 block tile, BK=32, 256 threads = 4 waves (2x2), wave tile 64x128
// (4x8 tiles of mfma_f32_16x16x32_bf16). Double-buffered LDS, one barrier/iter:
//   barrier -> issue tile k+1 loads (other buffer) -> compute tile k
// so the vmcnt(0) drain at the next barrier overlaps a full compute phase.
// ---------------------------------------------------------------------------
template<int EPILOGUE>
__global__ __launch_bounds__(256, 2)
void gemm_tn(const unsigned short* __restrict__ A,
             const unsigned short* __restrict__ Bt,
             const float* __restrict__ bias,
             void* __restrict__ Cout, int Nn, int K)
{
    __shared__ unsigned short sA[2][128 * 32];   // [buf][row][k], 64B rows
    __shared__ unsigned short sB[2][256 * 32];   // [buf][n][k]

    const int m0   = blockIdx.y * 128;
    const int n0   = blockIdx.x * 256;
    const int tid  = threadIdx.x;
    const int wave = tid >> 6;
    const int lane = tid & 63;
    const int wm   = wave & 1;    // wave row (2)
    const int wn   = wave >> 1;   // wave col (2)

    f32x4 acc[4][8];
    #pragma unroll
    for (int i = 0; i < 4; ++i)
        #pragma unroll
        for (int j = 0; j < 8; ++j)
            acc[i][j] = (f32x4){0.f, 0.f, 0.f, 0.f};

    // Staging: each chunk = 16 rows x 32 elems = 1 KB, one wave-instruction.
    // Wave w fills sA rows [32w, 32w+32) and sB rows [64w, 64w+64).
    const int laneRow = lane >> 2;          // 0..15
    const int laneCol = (lane & 3) * 8;     // element offset (16B)
    const unsigned short* gA0 = A  + (size_t)(m0 + wave * 32 + laneRow) * K + laneCol;
    const unsigned short* gA1 = gA0 + (size_t)16 * K;
    const unsigned short* gB0 = Bt + (size_t)(n0 + wave * 64 + laneRow) * K + laneCol;
    const unsigned short* gB1 = gB0 + (size_t)16 * K;
    const unsigned short* gB2 = gB0 + (size_t)32 * K;
    const unsigned short* gB3 = gB0 + (size_t)48 * K;
    const int lAo = wave * 1024;            // wave-uniform LDS bases (elements)
    const int lBo = wave * 2048;

    // fragment read offsets (elements) in the [128|256] x 32 tiles
    const int fa = (wm * 64  + (lane & 15)) * 32 + (lane >> 4) * 8;
    const int fb = (wn * 128 + (lane & 15)) * 32 + (lane >> 4) * 8;

    const int KT = K >> 5;

    // prologue: stage tile 0 into buf 0
    {
        async16(gA0, &sA[0][lAo]);
        async16(gA1, &sA[0][lAo + 512]);
        async16(gB0, &sB[0][lBo]);
        async16(gB1, &sB[0][lBo + 512]);
        async16(gB2, &sB[0][lBo + 1024]);
        async16(gB3, &sB[0][lBo + 1536]);
    }

    for (int kt = 0; kt < KT; ++kt) {
        const int buf = kt & 1;
        __syncthreads();   // drains tile-kt loads; also fences last iter's reads
        if (kt + 1 < KT) {
            const int k0 = (kt + 1) << 5;
            const int nb = buf ^ 1;
            async16(gA0 + k0, &sA[nb][lAo]);
            async16(gA1 + k0, &sA[nb][lAo + 512]);
            async16(gB0 + k0, &sB[nb][lBo]);
            async16(gB1 + k0, &sB[nb][lBo + 512]);
            async16(gB2 + k0, &sB[nb][lBo + 1024]);
            async16(gB3 + k0, &sB[nb][lBo + 1536]);
        }
        short8 af[4], bf[8];
        #pragma unroll
        for (int t = 0; t < 4; ++t) af[t] = *(const short8*)&sA[buf][fa + t * 512];
        #pragma unroll
        for (int t = 0; t < 8; ++t) bf[t] = *(const short8*)&sB[buf][fb + t * 512];
        #pragma unroll
        for (int i = 0; i < 4; ++i)
            #pragma unroll
            for (int j = 0; j < 8; ++j)
                acc[i][j] = __builtin_amdgcn_mfma_f32_16x16x32_bf16(
                    af[i], bf[j], acc[i][j], 0, 0, 0);
    }

    // Epilogue. C/D layout: col = lane&15, row = (lane>>4)*4 + reg
    const int cr = (lane >> 4) * 4;
    const int cc = lane & 15;
    #pragma unroll
    for (int j = 0; j < 8; ++j) {
        const int col = n0 + wn * 128 + j * 16 + cc;
        const float bv = bias[col];
        #pragma unroll
        for (int i = 0; i < 4; ++i) {
            const int rowBase = m0 + wm * 64 + i * 16 + cr;
            #pragma unroll
            for (int r = 0; r < 4; ++r) {
                float v = acc[i][j][r] + bv;
                if (EPILOGUE == 0) {
                    float s = v / (1.0f + __expf(-v));   // silu
                    ((unsigned short*)Cout)[(size_t)(rowBase + r) * Nn + col] = f2bf(s);
                } else {
                    ((float*)Cout)[(size_t)(rowBase + r) * Nn + col] = v;
                }
            }
        }
    }
}

// ---------------------------------------------------------------------------
// Soft-assign: q[n,k] = (1 + ||z_n - c_k||^2)^-1, row-normalized (V=1).
// One wave per row; clusters cached in LDS; butterfly reduce over 64 lanes.
// ---------------------------------------------------------------------------
__global__ __launch_bounds__(256)
void cluster_kernel(const float* __restrict__ z, const float* __restrict__ clusters,
                    float* __restrict__ q) {
    __shared__ float sc[NCLUST * H1];   // 20 KB
    const int tid = threadIdx.x;
    for (int i = tid; i < NCLUST * H1; i += 256) sc[i] = clusters[i];
    __syncthreads();

    const int wave = tid >> 6, lane = tid & 63;
    const int row = blockIdx.x * 4 + wave;   // grid = 8192 -> 32768 rows

    const float4 zv = ((const float4*)(z + (size_t)row * H1))[lane];

    float myq = 0.0f, qsum = 0.0f;
    #pragma unroll
    for (int k = 0; k < NCLUST; ++k) {
        const float4 cv = ((const float4*)(sc + k * H1))[lane];
        float dx = zv.x - cv.x, dy = zv.y - cv.y;
        float dz = zv.z - cv.z, dw = zv.w - cv.w;
        float p = dx * dx + dy * dy + dz * dz + dw * dw;
        #pragma unroll
        for (int s = 32; s >= 1; s >>= 1) p += __shfl_xor(p, s, 64);
        float qk = 1.0f / (1.0f + p);   // V=1
        qsum += qk;
        myq = (lane == k) ? qk : myq;
    }
    if (lane < NCLUST) q[(size_t)row * NCLUST + lane] = myq / qsum;
}

// ---------------------------------------------------------------------------
extern "C" void kernel_launch(void* const* d_in, const int* in_sizes, int n_in,
                              void* d_out, int out_size, void* d_ws, size_t ws_size,
                              hipStream_t stream) {
    const float* x        = (const float*)d_in[0];
    const float* W1       = (const float*)d_in[1];
    const float* b1       = (const float*)d_in[2];
    const float* W2       = (const float*)d_in[3];
    const float* b2       = (const float*)d_in[4];
    const float* clusters = (const float*)d_in[5];
    float* out = (float*)d_out;   // [32768*256 z fp32][32768*20 q fp32]

    // workspace layout (16B aligned)
    unsigned short* xb  = (unsigned short*)d_ws;                  // 32768*3072 bf16
    unsigned short* w1t = xb  + (size_t)N_ROWS * KPAD;            // 1024*3072 bf16
    unsigned short* w2t = w1t + (size_t)H0 * KPAD;                // 256*1024 bf16
    unsigned short* h   = w2t + (size_t)H1 * H0;                  // 32768*1024 bf16

    // 1) x -> bf16 (padded)
    hipLaunchKernelGGL(cvt_x, dim3((N_ROWS * 384) / 256), dim3(256), 0, stream, x, xb);
    // 2) W1 -> bf16 transposed+padded [1024][3072]
    hipLaunchKernelGGL(transpose_cvt, dim3(H0 / 32, KPAD / 32), dim3(32, 8), 0, stream,
                       W1, D_IN, H0, KPAD, w1t);
    // 3) W2 -> bf16 transposed [256][1024]
    hipLaunchKernelGGL(transpose_cvt, dim3(H1 / 32, H0 / 32), dim3(32, 8), 0, stream,
                       W2, H0, H1, H0, w2t);
    // 4) h = silu(xb @ W1 + b1)  [32768 x 1024] bf16
    hipLaunchKernelGGL((gemm_tn<0>), dim3(H0 / 256, N_ROWS / 128), dim3(256), 0, stream,
                       xb, w1t, b1, (void*)h, H0, KPAD);
    // 5) z = h @ W2 + b2  [32768 x 256] fp32 -> d_out
    hipLaunchKernelGGL((gemm_tn<1>), dim3(H1 / 256, N_ROWS / 128), dim3(256), 0, stream,
                       h, w2t, b2, (void*)out, H1, H0);
    // 6) q soft-assign -> d_out tail
    hipLaunchKernelGGL(cluster_kernel, dim3(N_ROWS / 4), dim3(256), 0, stream,
                       out, clusters, out + (size_t)N_ROWS * H1);
}